// Round 5
// baseline (328.481 us; speedup 1.0000x reference)
//
#include <hip/hip_runtime.h>

// Problem constants (fixed by setup_inputs).
constexpr int B_    = 4;
constexpr int N_    = 16384;
constexpr int M_    = 1024;
constexpr int C_    = 64;     // feature channels
constexpr int COP_  = 64;     // neighbor-op out channels
constexpr int COUT_ = 128;    // final out channels
constexpr int K_    = 32;     // neighbors
constexpr float R2_ = 0.25f;  // radius^2

typedef __attribute__((ext_vector_type(8)))  short bf16x8;   // MFMA A/B frag (4 VGPR)
typedef __attribute__((ext_vector_type(16))) float f32x16;   // MFMA C/D frag

// fp32 -> bf16 round-to-nearest-even (data is finite; NaN path not needed).
static __device__ __forceinline__ short f2bf(float f) {
    union { float f; unsigned u; } v; v.f = f;
    const unsigned r = v.u + 0x7fffu + ((v.u >> 16) & 1u);
    return (short)(r >> 16);
}

// One center per 2-wave block (8192 waves total -> 2x the latency-hiding of
// the R4 single-wave layout). Wave t owns neighbor-op N-tile t (channels
// [32t,32t+32)): it loads only its own W_op B-fragments (half of R4's), runs
// 5 MFMAs, pools its 32 channels, then after one barrier both waves aggregate
// to out channels [64t,64t+64) (half of R4's W_agg loads each).
// K-dim ordering: k=0..63 features, k=64..66 rel-pos, rest zero pad (K=80).
// A (32 neighbors x 80) loads from global directly in MFMA A-fragment layout
// (lane l: row m=l&31, k=(l>>5)*8+j => two aligned float4 per 16-step).
// C/D layout (verified m74/m101): col=lane&31, row=(reg&3)+8*(reg>>2)+4*(lane>>5).
__global__ __launch_bounds__(128) void pointnet_fused(
    const float* __restrict__ positions,   // (B,N,3)
    const float* __restrict__ features,    // (B,N,64)
    const float* __restrict__ centers,     // (B,M,3)
    const float* __restrict__ distances,   // (B,M,N)
    const float* __restrict__ W_op,        // (67,64)
    const float* __restrict__ b_op,        // (64)
    const float* __restrict__ W_agg,       // (64,128)
    const float* __restrict__ b_agg,       // (128)
    float* __restrict__ out)               // (B,M,128)
{
    const int lane = threadIdx.x & 63;
    const int wv   = threadIdx.x >> 6;     // N-tile 0 or 1
    const int bm   = blockIdx.x;           // center id
    const int b    = bm >> 10;             // bm / M_
    const int bN   = b * N_;

    __shared__ int   s_ids[2][K_];         // per-wave copy (no early barrier)
    __shared__ float s_pool[COP_];
    if (lane < K_) s_ids[wv][lane] = 0;    // safe default (masked by `valid`)

    // ---- Phase 1: ball query (both waves duplicate; identical results).
    // First 4 chunks (256 cols) load as independent dwords -> one latency.
    const float* drow = distances + (size_t)bm * N_;
    float dch[4];
    #pragma unroll
    for (int i = 0; i < 4; ++i) dch[i] = drow[64 * i + lane];
    const unsigned long long ltmask = (1ull << lane) - 1ull;
    int found = 0;
    #pragma unroll
    for (int i = 0; i < 4; ++i) {
        const bool pred = dch[i] < R2_;
        const unsigned long long mi = __ballot(pred);
        const int rank = found + __popcll(mi & ltmask);
        if (pred && rank < K_) s_ids[wv][rank] = 64 * i + lane;
        found += (int)__popcll(mi);
    }
    for (int n0 = 256; n0 < N_ && found < K_; n0 += 64) {   // ~never taken
        const float d = drow[n0 + lane];
        const bool pred = d < R2_;
        const unsigned long long mi = __ballot(pred);
        const int rank = found + __popcll(mi & ltmask);
        if (pred && rank < K_) s_ids[wv][rank] = n0 + lane;
        found += (int)__popcll(mi);
    }
    const int valid = found < K_ ? found : K_;   // wave-uniform

    const float ctr0 = centers[bm * 3 + 0];
    const float ctr1 = centers[bm * 3 + 1];
    const float ctr2 = centers[bm * 3 + 2];

    // Lane l serves A-matrix row m = l&31 (both half-waves read the same id).
    const int rowid = s_ids[wv][lane & (K_ - 1)];
    const int koff  = (lane >> 5) * 8;           // 0 or 8: k-subrange of this half

    // ---- Phase 2a: A fragments straight from global (independent loads) ----
    const float* frow = features + (size_t)(bN + rowid) * C_;
    float4 xa[8];
    #pragma unroll
    for (int s = 0; s < 4; ++s) {
        xa[2 * s]     = *(const float4*)(frow + 16 * s + koff);
        xa[2 * s + 1] = *(const float4*)(frow + 16 * s + koff + 4);
    }
    const float* prow = positions + (size_t)(bN + rowid) * 3;
    const float r0 = prow[0] - ctr0;             // used by lanes with koff==0
    const float r1 = prow[1] - ctr1;
    const float r2 = prow[2] - ctr2;

    bf16x8 afr[5];
    #pragma unroll
    for (int s = 0; s < 4; ++s) {
        afr[s][0] = f2bf(xa[2 * s].x);     afr[s][1] = f2bf(xa[2 * s].y);
        afr[s][2] = f2bf(xa[2 * s].z);     afr[s][3] = f2bf(xa[2 * s].w);
        afr[s][4] = f2bf(xa[2 * s + 1].x); afr[s][5] = f2bf(xa[2 * s + 1].y);
        afr[s][6] = f2bf(xa[2 * s + 1].z); afr[s][7] = f2bf(xa[2 * s + 1].w);
    }
    #pragma unroll
    for (int j = 0; j < 8; ++j) afr[4][j] = 0;   // step 4: rel-pos + pad
    if (koff == 0) { afr[4][0] = f2bf(r0); afr[4][1] = f2bf(r1); afr[4][2] = f2bf(r2); }

    // ---- Phase 2b: this wave's W_op B-fragments (N-tile `wv`) ----
    const int n0col = lane & 31;
    const int ncol  = 32 * wv + n0col;
    bf16x8 bfr[5];
    #pragma unroll
    for (int s = 0; s < 4; ++s)                  // k = 16s+koff+j < 64: features
        #pragma unroll
        for (int j = 0; j < 8; ++j)
            bfr[s][j] = f2bf(W_op[(3 + 16 * s + koff + j) * COP_ + ncol]);
    #pragma unroll
    for (int j = 0; j < 8; ++j) {                // k >= 64: rel-pos rows / pad
        const int c = koff + j;
        bfr[4][j] = (c < 3) ? f2bf(W_op[c * COP_ + ncol]) : (short)0;
    }

    // ---- Phase 3: 5 MFMAs ----
    f32x16 acc;
    #pragma unroll
    for (int i = 0; i < 16; ++i) acc[i] = 0.0f;
    #pragma unroll
    for (int s = 0; s < 5; ++s)
        acc = __builtin_amdgcn_mfma_f32_32x32x16_bf16(afr[s], bfr[s], acc, 0, 0, 0);

    // ---- bias + mask (reference zero-row trick) + max over neighbors ----
    const float bb = b_op[ncol];
    const int mbase = 4 * (lane >> 5);
    float p = -INFINITY;
    #pragma unroll
    for (int r = 0; r < 16; ++r) {
        const int m = (r & 3) + 8 * (r >> 2) + mbase;  // neighbor slot of this reg
        p = fmaxf(p, (m < valid) ? (acc[r] + bb) : 0.0f);
    }
    p = fmaxf(p, __shfl_xor(p, 32));   // combine the two half-wave row sets
    // All lanes of wave wv: p = pooled[32*wv + (lane&31)].

    if (lane < 32) s_pool[ncol] = p;
    __syncthreads();
    const float pfull = s_pool[lane];  // lane j holds pooled[j], j=0..63

    // ---- Phase 4: aggregation, wave wv -> out channels [64wv, 64wv+64) ----
    float a = b_agg[64 * wv + lane];
    #pragma unroll
    for (int jj = 0; jj < COP_; ++jj) {
        const float q = __int_as_float(
            __builtin_amdgcn_readlane(__float_as_int(pfull), jj));
        a = fmaf(q, W_agg[jj * COUT_ + 64 * wv + lane], a);
    }
    out[(size_t)bm * COUT_ + 64 * wv + lane] = fmaxf(a, 0.0f);
}

extern "C" void kernel_launch(void* const* d_in, const int* in_sizes, int n_in,
                              void* d_out, int out_size, void* d_ws, size_t ws_size,
                              hipStream_t stream) {
    const float* positions = (const float*)d_in[0];
    const float* features  = (const float*)d_in[1];
    const float* centers   = (const float*)d_in[2];
    const float* distances = (const float*)d_in[3];
    const float* W_op      = (const float*)d_in[4];
    const float* b_op      = (const float*)d_in[5];
    const float* W_agg     = (const float*)d_in[6];
    const float* b_agg     = (const float*)d_in[7];
    float* out = (float*)d_out;

    dim3 grid(B_ * M_);   // 4096 blocks, 2 waves each (8192 waves)
    dim3 block(128);
    pointnet_fused<<<grid, block, 0, stream>>>(
        positions, features, centers, distances,
        W_op, b_op, W_agg, b_agg, out);
}

// Round 6
// 327.765 us; speedup vs baseline: 1.0022x; 1.0022x over previous
//
#include <hip/hip_runtime.h>

// Problem constants (fixed by setup_inputs).
constexpr int B_    = 4;
constexpr int N_    = 16384;
constexpr int M_    = 1024;
constexpr int C_    = 64;     // feature channels
constexpr int COP_  = 64;     // neighbor-op out channels
constexpr int COUT_ = 128;    // final out channels
constexpr int K_    = 32;     // neighbors
constexpr float R2_ = 0.25f;  // radius^2

typedef __attribute__((ext_vector_type(8)))  short bf16x8;   // MFMA A/B frag (4 VGPR)
typedef __attribute__((ext_vector_type(16))) float f32x16;   // MFMA C/D frag

// fp32 -> bf16 round-to-nearest-even (data is finite; NaN path not needed).
static __device__ __forceinline__ short f2bf(float f) {
    union { float f; unsigned u; } v; v.f = f;
    const unsigned r = v.u + 0x7fffu + ((v.u >> 16) & 1u);
    return (short)(r >> 16);
}

// R4 structure (best measured): one wave per center, 4096 single-wave blocks,
// no barriers. R6 change: ISSUE ORDER. Distance chunk-loads go out first;
// all block-invariant loads (centers, b_op, b_agg, W_op B-fragments) issue
// before the ballot consumes the distances, so weight-load latency hides
// under the cold-HBM distance latency instead of serializing after the scan.
//
// K-dim ordering for the neighbor-op GEMM: k=0..63 features, k=64..66
// rel-pos, rest zero pad (K=80 = 5 x 16-steps of v_mfma_f32_32x32x16_bf16).
// A (32 neighbors x 80) loads from global directly in MFMA A-fragment layout
// (lane l: row m=l&31, k=(l>>5)*8+j => two aligned float4 per step).
// C/D layout (verified m74/m101): col=lane&31, row=(reg&3)+8*(reg>>2)+4*(lane>>5).
__global__ __launch_bounds__(64) void pointnet_fused(
    const float* __restrict__ positions,   // (B,N,3)
    const float* __restrict__ features,    // (B,N,64)
    const float* __restrict__ centers,     // (B,M,3)
    const float* __restrict__ distances,   // (B,M,N)
    const float* __restrict__ W_op,        // (67,64)
    const float* __restrict__ b_op,        // (64)
    const float* __restrict__ W_agg,       // (64,128)
    const float* __restrict__ b_agg,       // (128)
    float* __restrict__ out)               // (B,M,128)
{
    const int lane = threadIdx.x;          // 0..63
    const int bm   = blockIdx.x;           // center id
    const int b    = bm >> 10;             // bm / M_
    const int bN   = b * N_;

    __shared__ int s_ids[K_];
    if (lane < K_) s_ids[lane] = 0;        // safe default (masked by `valid`)

    // ---- Issue the cold distance loads FIRST (4 independent chunks). ----
    const float* drow = distances + (size_t)bm * N_;
    float dch[4];
    #pragma unroll
    for (int i = 0; i < 4; ++i) dch[i] = drow[64 * i + lane];

    // ---- Block-invariant loads overlap the distance latency. ----
    const float ctr0 = centers[bm * 3 + 0];
    const float ctr1 = centers[bm * 3 + 1];
    const float ctr2 = centers[bm * 3 + 2];
    const int   n0col = lane & 31;
    const int   koff  = (lane >> 5) * 8;         // 0 or 8: k-subrange of half-wave
    const float bb0 = b_op[n0col];
    const float bb1 = b_op[32 + n0col];
    const float bg0 = b_agg[lane];
    const float bg1 = b_agg[lane + 64];

    bf16x8 bfr[2][5];                            // W_op B-fragments, 2 N-tiles
    #pragma unroll
    for (int t = 0; t < 2; ++t) {
        const int n = 32 * t + n0col;
        #pragma unroll
        for (int s = 0; s < 4; ++s)              // k = 16s+koff+j < 64: features
            #pragma unroll
            for (int j = 0; j < 8; ++j)
                bfr[t][s][j] = f2bf(W_op[(3 + 16 * s + koff + j) * COP_ + n]);
        #pragma unroll
        for (int j = 0; j < 8; ++j) {            // k >= 64: rel-pos rows / pad
            const int c = koff + j;
            bfr[t][4][j] = (c < 3) ? f2bf(W_op[c * COP_ + n]) : (short)0;
        }
    }

    // ---- Phase 1: ball query on the prefetched chunks. ----
    const unsigned long long ltmask = (1ull << lane) - 1ull;
    int found = 0;
    #pragma unroll
    for (int i = 0; i < 4; ++i) {
        const bool pred = dch[i] < R2_;
        const unsigned long long mi = __ballot(pred);
        const int rank = found + __popcll(mi & ltmask);
        if (pred && rank < K_) s_ids[rank] = 64 * i + lane;
        found += (int)__popcll(mi);
    }
    for (int n0 = 256; n0 < N_ && found < K_; n0 += 64) {   // ~never taken
        const float d = drow[n0 + lane];
        const bool pred = d < R2_;
        const unsigned long long mi = __ballot(pred);
        const int rank = found + __popcll(mi & ltmask);
        if (pred && rank < K_) s_ids[rank] = n0 + lane;
        found += (int)__popcll(mi);
    }
    const int valid = found < K_ ? found : K_;   // wave-uniform

    // Lane l serves A-matrix row m = l&31 (both half-waves read the same id).
    const int rowid = s_ids[lane & (K_ - 1)];

    // ---- Phase 2: A fragments straight from global (independent loads) ----
    const float* frow = features + (size_t)(bN + rowid) * C_;
    float4 xa[8];
    #pragma unroll
    for (int s = 0; s < 4; ++s) {
        xa[2 * s]     = *(const float4*)(frow + 16 * s + koff);
        xa[2 * s + 1] = *(const float4*)(frow + 16 * s + koff + 4);
    }
    const float* prow = positions + (size_t)(bN + rowid) * 3;
    const float r0 = prow[0] - ctr0;             // used by lanes with koff==0
    const float r1 = prow[1] - ctr1;
    const float r2 = prow[2] - ctr2;

    bf16x8 afr[5];
    #pragma unroll
    for (int s = 0; s < 4; ++s) {
        afr[s][0] = f2bf(xa[2 * s].x);     afr[s][1] = f2bf(xa[2 * s].y);
        afr[s][2] = f2bf(xa[2 * s].z);     afr[s][3] = f2bf(xa[2 * s].w);
        afr[s][4] = f2bf(xa[2 * s + 1].x); afr[s][5] = f2bf(xa[2 * s + 1].y);
        afr[s][6] = f2bf(xa[2 * s + 1].z); afr[s][7] = f2bf(xa[2 * s + 1].w);
    }
    #pragma unroll
    for (int j = 0; j < 8; ++j) afr[4][j] = 0;   // step 4: rel-pos + pad
    if (koff == 0) { afr[4][0] = f2bf(r0); afr[4][1] = f2bf(r1); afr[4][2] = f2bf(r2); }

    // ---- Phase 3: 10 MFMAs ----
    f32x16 acc0, acc1;
    #pragma unroll
    for (int i = 0; i < 16; ++i) { acc0[i] = 0.0f; acc1[i] = 0.0f; }
    #pragma unroll
    for (int s = 0; s < 5; ++s) {
        acc0 = __builtin_amdgcn_mfma_f32_32x32x16_bf16(afr[s], bfr[0][s], acc0, 0, 0, 0);
        acc1 = __builtin_amdgcn_mfma_f32_32x32x16_bf16(afr[s], bfr[1][s], acc1, 0, 0, 0);
    }

    // ---- bias + mask (reference zero-row trick) + max over neighbors ----
    const int mbase = 4 * (lane >> 5);
    float p0 = -INFINITY, p1 = -INFINITY;
    #pragma unroll
    for (int r = 0; r < 16; ++r) {
        const int m = (r & 3) + 8 * (r >> 2) + mbase;  // neighbor slot of this reg
        const bool ok = m < valid;
        p0 = fmaxf(p0, ok ? (acc0[r] + bb0) : 0.0f);
        p1 = fmaxf(p1, ok ? (acc1[r] + bb1) : 0.0f);
    }
    p0 = fmaxf(p0, __shfl_xor(p0, 32));   // combine the two half-wave row sets
    p1 = fmaxf(p1, __shfl_xor(p1, 32));
    // Now every lane: p0 = pooled[lane&31], p1 = pooled[32+(lane&31)].

    // ---- Phase 4: aggregation 64 -> 128 + ReLU (readlane broadcast) ----
    float a0 = bg0;
    float a1 = bg1;
    #pragma unroll
    for (int jj = 0; jj < 32; ++jj) {
        const float q0 = __int_as_float(__builtin_amdgcn_readlane(__float_as_int(p0), jj));
        a0 = fmaf(q0, W_agg[jj * COUT_ + lane],      a0);
        a1 = fmaf(q0, W_agg[jj * COUT_ + lane + 64], a1);
        const float q1 = __int_as_float(__builtin_amdgcn_readlane(__float_as_int(p1), jj));
        a0 = fmaf(q1, W_agg[(32 + jj) * COUT_ + lane],      a0);
        a1 = fmaf(q1, W_agg[(32 + jj) * COUT_ + lane + 64], a1);
    }
    float* orow = out + (size_t)bm * COUT_;
    orow[lane]      = fmaxf(a0, 0.0f);
    orow[lane + 64] = fmaxf(a1, 0.0f);
}

extern "C" void kernel_launch(void* const* d_in, const int* in_sizes, int n_in,
                              void* d_out, int out_size, void* d_ws, size_t ws_size,
                              hipStream_t stream) {
    const float* positions = (const float*)d_in[0];
    const float* features  = (const float*)d_in[1];
    const float* centers   = (const float*)d_in[2];
    const float* distances = (const float*)d_in[3];
    const float* W_op      = (const float*)d_in[4];
    const float* b_op      = (const float*)d_in[5];
    const float* W_agg     = (const float*)d_in[6];
    const float* b_agg     = (const float*)d_in[7];
    float* out = (float*)d_out;

    dim3 grid(B_ * M_);   // 4096 single-wave blocks
    dim3 block(64);
    pointnet_fused<<<grid, block, 0, stream>>>(
        positions, features, centers, distances,
        W_op, b_op, W_agg, b_agg, out);
}